// Round 4
// baseline (1211.758 us; speedup 1.0000x reference)
//
#include <hip/hip_runtime.h>

typedef unsigned short u16;
typedef unsigned int u32;
typedef __attribute__((ext_vector_type(8))) short short8;
typedef __attribute__((ext_vector_type(4))) float floatx4;
typedef __attribute__((ext_vector_type(4))) float float4v;

#define B_ 32
#define T_ 168
#define NH_ 32
#define NM_ 64
#define E_ 384
#define HL_ 128
#define FUT_ 24
#define SLOPE_ 0.01f
#define XP_ 80    // xbuf stride per batch (u16): +8 banks/batch -> <=2-way (free)
#define HP_ 144   // hbuf stride per batch (u16)
#define WIH_LP 72  // Wih staging row stride (u16): +4 banks/row
#define WHH_LP 136 // Whh staging row stride (u16): +4 banks/row
#define OVL_E (T_ * 4 * XP_)  // 53760 u16 = 107.5 KB (>= 128*WIH_LP+128*WHH_LP = 26624)

static __device__ __forceinline__ float b2f(u16 u) {
  u32 v = ((u32)u) << 16;
  return __builtin_bit_cast(float, v);
}
static __device__ __forceinline__ u16 f2bf(float f) {
  u32 x = __builtin_bit_cast(u32, f);
  u32 r = (x + 0x7fffu + ((x >> 16) & 1u)) >> 16;
  return (u16)r;
}
static __device__ __forceinline__ float fexp2(float x) { return __builtin_amdgcn_exp2f(x); }
static __device__ __forceinline__ float frcp(float x) { return __builtin_amdgcn_rcpf(x); }
static __device__ __forceinline__ float sigm(float x) {
  return frcp(1.0f + fexp2(-1.4426950408889634f * x));
}
static __device__ __forceinline__ float tanh_fast(float x) {
  return 1.0f - 2.0f * frcp(1.0f + fexp2(2.8853900817779268f * x));
}
static __device__ __forceinline__ float sel4(floatx4 v, int r) {
  float m0 = (r & 1) ? v[1] : v[0];
  float m1 = (r & 1) ? v[3] : v[2];
  return (r & 2) ? m1 : m0;
}
static __device__ __forceinline__ float lrelu(float x) { return fmaxf(x, SLOPE_ * x); }

// Fully fused GNN + per-station LSTM + head.
// Grid: 256 WGs = 32 stations x 8 batch-groups (4 batches). 512 thr = 8 waves.
__launch_bounds__(512, 2)
__global__ void fused_kernel(const float* __restrict__ dm, const float* __restrict__ dh,
                             const int* __restrict__ eidx,
                             const float* __restrict__ Wroot, const float* __restrict__ Wrel,
                             const float* __restrict__ bgnn,
                             const float* __restrict__ Wih, const float* __restrict__ Whh,
                             const float* __restrict__ bih, const float* __restrict__ bhh,
                             const float* __restrict__ Wlin, const float* __restrict__ blin,
                             float* __restrict__ out) {
  const int s = blockIdx.x & 31;
  const int bg = blockIdx.x >> 5;
  const int tid = threadIdx.x;
  const int w = tid >> 6;
  const int lane = tid & 63;
  const int cm = lane & 15;
  const int q = lane >> 4;
  const int b = cm & 3;
  const int rho = cm >> 2;

  // ovl: first weight staging (per-block), then xbuf (GNN features)
  __shared__ __align__(16) u16 ovl[OVL_E];
  __shared__ __align__(16) u16 hbuf[2 * 4 * HP_];
  __shared__ float xh_lds[4][T_];
  __shared__ float ag_lds[4][T_];
  __shared__ float wr_s[64], wv_s[64], bg_s[64];
  __shared__ int srcs[E_];
  __shared__ int nsrc, iflag;

  // ---- A: init
  if (tid == 0) { nsrc = 0; iflag = 0; }
  for (int i = tid; i < 2 * 4 * HP_; i += 512) hbuf[i] = 0;
  __syncthreads();

  // ---- B: int64-vs-int32 edge_index probe
  {
    int odd = 0;
    for (int e = tid; e < E_; e += 512) odd |= eidx[2 * e + 1];
    if (odd) atomicOr(&iflag, 1);
  }
  __syncthreads();
  const bool i32 = iflag != 0;

  // ---- C: in-edges for this station; stage small tensors
  for (int e = tid; e < E_; e += 512) {
    int se = i32 ? eidx[e] : eidx[2 * e];
    int de = i32 ? eidx[E_ + e] : eidx[2 * E_ + 2 * e];
    if (de == s) { int i = atomicAdd(&nsrc, 1); srcs[i] = se; }
  }
  if (tid < 64) { wr_s[tid] = Wroot[tid]; wv_s[tid] = Wrel[tid]; bg_s[tid] = bgnn[tid]; }
  for (int i = tid; i < 4 * T_; i += 512) {
    int bb = i / T_, t = i % T_;
    xh_lds[bb][t] = dh[((size_t)(bg * 4 + bb) * T_ + t) * NH_ + s];
  }
  // bias while global pipe is free
  floatx4 bias_init[4];
#pragma unroll
  for (int blk = 0; blk < 4; blk++)
#pragma unroll
    for (int r = 0; r < 4; r++) {
      const int nb = blk * 128 + w * 16 + q * 4 + r;
      bias_init[blk][r] = bih[s * 512 + nb] + bhh[s * 512 + nb];
    }
  __syncthreads();

  // ---- D: per-(b,t) graph aggregation (avg ~4 in-edges/station)
  const int ns = nsrc;
  for (int i = tid; i < 4 * T_; i += 512) {
    int bb = i / T_, t = i % T_;
    size_t gb = (size_t)(bg * 4 + bb) * T_ + t;
    float a = 0.f;
    for (int j = 0; j < ns; j++) {
      int sr = srcs[j];
      a += (sr < NH_) ? dh[gb * NH_ + sr] : dm[gb * NM_ + (sr - NH_)];
    }
    ag_lds[bb][t] = a;
  }

  // ---- W: coalesced LDS-staged weight load, one gate-block (128 rows) at a time
  short8 Af[4][6];
#pragma unroll 1
  for (int blk = 0; blk < 4; blk++) {
    __syncthreads();  // previous block's fragment reads / phase D done
    const float* gih = Wih + ((size_t)s * 512 + blk * 128) * 64;
#pragma unroll
    for (int it = 0; it < 4; it++) {  // 2048 float4s / 512 thr
      int j = tid + it * 512;
      float4v v = *(const float4v*)(gih + 4 * j);
      u16* dst = ovl + (j >> 4) * WIH_LP + (j & 15) * 4;
      dst[0] = f2bf(v[0]); dst[1] = f2bf(v[1]); dst[2] = f2bf(v[2]); dst[3] = f2bf(v[3]);
    }
    const float* ghh = Whh + ((size_t)s * 512 + blk * 128) * 128;
#pragma unroll
    for (int it = 0; it < 8; it++) {  // 4096 float4s / 512 thr
      int j = tid + it * 512;
      float4v v = *(const float4v*)(ghh + 4 * j);
      u16* dst = ovl + 128 * WIH_LP + (j >> 5) * WHH_LP + (j & 31) * 4;
      dst[0] = f2bf(v[0]); dst[1] = f2bf(v[1]); dst[2] = f2bf(v[2]); dst[3] = f2bf(v[3]);
    }
    __syncthreads();
    const int nl = w * 16 + cm;
#pragma unroll
    for (int kk = 0; kk < 2; kk++)
      Af[blk][kk] = *(const short8*)(ovl + nl * WIH_LP + kk * 32 + q * 8);
#pragma unroll
    for (int kk = 0; kk < 4; kk++)
      Af[blk][2 + kk] = *(const short8*)(ovl + 128 * WIH_LP + nl * WHH_LP + kk * 32 + q * 8);
  }
  __syncthreads();

  // ---- E: precompute GNN features into xbuf (= ovl, weights now in registers)
  {
    const int k = tid & 63;
    const int bb = (tid >> 6) & 3;
    const int th = tid >> 8;
    const float wrk = wr_s[k], wvk = wv_s[k], bgk = bg_s[k];
    for (int i = 0; i < T_ / 2; i++) {
      const int t = th * (T_ / 2) + i;
      const float xv = xh_lds[bb][t] * wrk + ag_lds[bb][t] * wvk + bgk;
      ovl[t * (4 * XP_) + bb * XP_ + k] = f2bf(lrelu(xv));
    }
  }
  __syncthreads();

  // ---- recurrent loop: 24 MFMA/wave/step (8 independent 3-deep chains), 1 barrier
  const floatx4 zero4 = {0.f, 0.f, 0.f, 0.f};
  short8 BxN[2];
#pragma unroll
  for (int kk = 0; kk < 2; kk++)
    BxN[kk] = *(const short8*)(ovl + b * XP_ + kk * 32 + q * 8);
  float c = 0.0f;
#pragma unroll 2
  for (int t = 0; t < T_; t++) {
    const int p = t & 1, pn = p ^ 1;
    const short8 Bx0 = BxN[0], Bx1 = BxN[1];
    short8 Bh[4];
#pragma unroll
    for (int kk = 0; kk < 4; kk++)
      Bh[kk] = *(const short8*)(hbuf + p * (4 * HP_) + b * HP_ + kk * 32 + q * 8);

    floatx4 a1[4], a2[4];
#pragma unroll
    for (int blk = 0; blk < 4; blk++) {
      a1[blk] = __builtin_amdgcn_mfma_f32_16x16x32_bf16(Af[blk][2], Bh[0], bias_init[blk], 0, 0, 0);
      a2[blk] = __builtin_amdgcn_mfma_f32_16x16x32_bf16(Af[blk][3], Bh[1], zero4, 0, 0, 0);
    }
#pragma unroll
    for (int blk = 0; blk < 4; blk++) {
      a1[blk] = __builtin_amdgcn_mfma_f32_16x16x32_bf16(Af[blk][4], Bh[2], a1[blk], 0, 0, 0);
      a2[blk] = __builtin_amdgcn_mfma_f32_16x16x32_bf16(Af[blk][5], Bh[3], a2[blk], 0, 0, 0);
    }
#pragma unroll
    for (int blk = 0; blk < 4; blk++) {
      a1[blk] = __builtin_amdgcn_mfma_f32_16x16x32_bf16(Af[blk][0], Bx0, a1[blk], 0, 0, 0);
      a2[blk] = __builtin_amdgcn_mfma_f32_16x16x32_bf16(Af[blk][1], Bx1, a2[blk], 0, 0, 0);
    }
    // prefetch next step's x-fragments (no barrier dependence)
    if (t + 1 < T_) {
#pragma unroll
      for (int kk = 0; kk < 2; kk++)
        BxN[kk] = *(const short8*)(ovl + (t + 1) * (4 * XP_) + b * XP_ + kk * 32 + q * 8);
    }
    const float gi = sel4(a1[0], rho) + sel4(a2[0], rho);
    const float gf = sel4(a1[1], rho) + sel4(a2[1], rho);
    const float gg = sel4(a1[2], rho) + sel4(a2[2], rho);
    const float go = sel4(a1[3], rho) + sel4(a2[3], rho);
    c = sigm(gf) * c + sigm(gi) * tanh_fast(gg);
    const float hh = sigm(go) * tanh_fast(c);
    hbuf[pn * (4 * HP_) + b * HP_ + w * 16 + q * 4 + rho] = f2bf(hh);
    __syncthreads();
  }

  // ---- head
  if (tid < 4 * FUT_) {
    const int bb = tid / FUT_;
    const int f = tid % FUT_;
    float a = blin[f];
#pragma unroll 8
    for (int k = 0; k < HL_; k++) a += b2f(hbuf[bb * HP_ + k]) * Wlin[f * HL_ + k];
    out[((size_t)(bg * 4 + bb) * NH_ + s) * FUT_ + f] = lrelu(a);
  }
}

extern "C" void kernel_launch(void* const* d_in, const int* in_sizes, int n_in,
                              void* d_out, int out_size, void* d_ws, size_t ws_size,
                              hipStream_t stream) {
  const float* dm = (const float*)d_in[0];
  const float* dh = (const float*)d_in[1];
  const int* eidx = (const int*)d_in[2];
  const float* Wroot = (const float*)d_in[3];
  const float* Wrel = (const float*)d_in[4];
  const float* bgnn = (const float*)d_in[5];
  const float* Wih = (const float*)d_in[6];
  const float* Whh = (const float*)d_in[7];
  const float* bih = (const float*)d_in[8];
  const float* bhh = (const float*)d_in[9];
  const float* Wlin = (const float*)d_in[10];
  const float* blin = (const float*)d_in[11];
  float* out = (float*)d_out;

  fused_kernel<<<256, 512, 0, stream>>>(dm, dh, eidx, Wroot, Wrel, bgnn, Wih, Whh,
                                        bih, bhh, Wlin, blin, out);
}

// Round 5
// 190.739 us; speedup vs baseline: 6.3530x; 6.3530x over previous
//
#include <hip/hip_runtime.h>

typedef unsigned short u16;
typedef unsigned int u32;
typedef __attribute__((ext_vector_type(8))) short short8;
typedef __attribute__((ext_vector_type(4))) float floatx4;
typedef __attribute__((ext_vector_type(4))) float float4v;

#define B_ 32
#define T_ 168
#define NH_ 32
#define NM_ 64
#define E_ 384
#define HL_ 128
#define FUT_ 24
#define SLOPE_ 0.01f
#define XP_ 80     // xbuf stride per batch (u16)
#define HP_ 144    // hbuf stride per batch (u16)
#define WIH_LP 72  // Wih staging row stride (u16): 512*72 = 36864 u16 fits ovl
#define WHH_LP 136 // Whh staging row stride (u16): 256*136 = 34816 u16 fits ovl
#define OVL_E (T_ * 4 * XP_)  // 53760 u16 = 107.5 KB

static __device__ __forceinline__ float b2f(u16 u) {
  u32 v = ((u32)u) << 16;
  return __builtin_bit_cast(float, v);
}
static __device__ __forceinline__ u16 f2bf(float f) {
  u32 x = __builtin_bit_cast(u32, f);
  u32 r = (x + 0x7fffu + ((x >> 16) & 1u)) >> 16;
  return (u16)r;
}
static __device__ __forceinline__ float fexp2(float x) { return __builtin_amdgcn_exp2f(x); }
static __device__ __forceinline__ float frcp(float x) { return __builtin_amdgcn_rcpf(x); }
static __device__ __forceinline__ float sigm(float x) {
  return frcp(1.0f + fexp2(-1.4426950408889634f * x));
}
static __device__ __forceinline__ float tanh_fast(float x) {
  return 1.0f - 2.0f * frcp(1.0f + fexp2(2.8853900817779268f * x));
}
static __device__ __forceinline__ float sel4(floatx4 v, int r) {
  float m0 = (r & 1) ? v[1] : v[0];
  float m1 = (r & 1) ? v[3] : v[2];
  return (r & 2) ? m1 : m0;
}
static __device__ __forceinline__ float lrelu(float x) { return fmaxf(x, SLOPE_ * x); }

// Fully fused GNN + per-station LSTM + head.
// Grid: 256 WGs = 32 stations x 8 batch-groups (4 batches). 512 thr = 8 waves.
__launch_bounds__(512, 2)
__global__ void fused_kernel(const float* __restrict__ dm, const float* __restrict__ dh,
                             const int* __restrict__ eidx,
                             const float* __restrict__ Wroot, const float* __restrict__ Wrel,
                             const float* __restrict__ bgnn,
                             const float* __restrict__ Wih, const float* __restrict__ Whh,
                             const float* __restrict__ bih, const float* __restrict__ bhh,
                             const float* __restrict__ Wlin, const float* __restrict__ blin,
                             float* __restrict__ out) {
  const int s = blockIdx.x & 31;
  const int bg = blockIdx.x >> 5;
  const int tid = threadIdx.x;
  const int w = tid >> 6;
  const int lane = tid & 63;
  const int cm = lane & 15;
  const int q = lane >> 4;
  const int b = cm & 3;
  const int rho = cm >> 2;

  // ovl: weight staging rounds first, then xbuf (GNN features)
  __shared__ __align__(16) u16 ovl[OVL_E];
  __shared__ __align__(16) u16 hbuf[2 * 4 * HP_];
  __shared__ float xh_lds[4][T_];
  __shared__ float ag_lds[4][T_];
  __shared__ float wr_s[64], wv_s[64], bg_s[64];
  __shared__ int srcs[E_];
  __shared__ int nsrc, iflag;

  // ---- A: init
  if (tid == 0) { nsrc = 0; iflag = 0; }
  for (int i = tid; i < 2 * 4 * HP_; i += 512) hbuf[i] = 0;
  __syncthreads();

  // ---- B: int64-vs-int32 edge_index probe
  {
    int odd = 0;
    for (int e = tid; e < E_; e += 512) odd |= eidx[2 * e + 1];
    if (odd) atomicOr(&iflag, 1);
  }
  __syncthreads();
  const bool i32 = iflag != 0;

  // ---- C: in-edges for this station; stage small tensors; bias
  for (int e = tid; e < E_; e += 512) {
    int se = i32 ? eidx[e] : eidx[2 * e];
    int de = i32 ? eidx[E_ + e] : eidx[2 * E_ + 2 * e];
    if (de == s) { int i = atomicAdd(&nsrc, 1); srcs[i] = se; }
  }
  if (tid < 64) { wr_s[tid] = Wroot[tid]; wv_s[tid] = Wrel[tid]; bg_s[tid] = bgnn[tid]; }
  for (int i = tid; i < 4 * T_; i += 512) {
    int bb = i / T_, t = i % T_;
    xh_lds[bb][t] = dh[((size_t)(bg * 4 + bb) * T_ + t) * NH_ + s];
  }
  floatx4 bias_init[4];
#pragma unroll
  for (int blk = 0; blk < 4; blk++)
#pragma unroll
    for (int r = 0; r < 4; r++) {
      const int nb = blk * 128 + w * 16 + q * 4 + r;
      bias_init[blk][r] = bih[s * 512 + nb] + bhh[s * 512 + nb];
    }
  __syncthreads();

  // ---- D: per-(b,t) graph aggregation (avg ~4 in-edges/station)
  const int ns = nsrc;
  for (int i = tid; i < 4 * T_; i += 512) {
    int bb = i / T_, t = i % T_;
    size_t gb = (size_t)(bg * 4 + bb) * T_ + t;
    float a = 0.f;
    for (int j = 0; j < ns; j++) {
      int sr = srcs[j];
      a += (sr < NH_) ? dh[gb * NH_ + sr] : dm[gb * NM_ + (sr - NH_)];
    }
    ag_lds[bb][t] = a;
  }

  // ---- W: coalesced LDS-staged weight load, THREE fully-unrolled rounds.
  // Af indices are static everywhere -> guaranteed register residency.
  short8 Af[4][6];
  const int nl = w * 16 + cm;  // this lane's gate-row within a 128-block
  // Round 1: all of Wih (512 rows x 64)
  __syncthreads();
  {
    const float* g = Wih + (size_t)s * 512 * 64;
#pragma unroll
    for (int it = 0; it < 16; it++) {
      int j = tid + it * 512;
      float4v v = *(const float4v*)(g + 4 * j);
      u16* dst = ovl + (j >> 4) * WIH_LP + (j & 15) * 4;
      dst[0] = f2bf(v[0]); dst[1] = f2bf(v[1]); dst[2] = f2bf(v[2]); dst[3] = f2bf(v[3]);
    }
  }
  __syncthreads();
#pragma unroll
  for (int blk = 0; blk < 4; blk++)
#pragma unroll
    for (int kk = 0; kk < 2; kk++)
      Af[blk][kk] = *(const short8*)(ovl + (blk * 128 + nl) * WIH_LP + kk * 32 + q * 8);
  __syncthreads();
  // Round 2: Whh rows 0..255 (gate blocks 0,1)
  {
    const float* g = Whh + (size_t)s * 512 * 128;
#pragma unroll
    for (int it = 0; it < 16; it++) {
      int j = tid + it * 512;
      float4v v = *(const float4v*)(g + 4 * j);
      u16* dst = ovl + (j >> 5) * WHH_LP + (j & 31) * 4;
      dst[0] = f2bf(v[0]); dst[1] = f2bf(v[1]); dst[2] = f2bf(v[2]); dst[3] = f2bf(v[3]);
    }
  }
  __syncthreads();
#pragma unroll
  for (int blk = 0; blk < 2; blk++)
#pragma unroll
    for (int kk = 0; kk < 4; kk++)
      Af[blk][2 + kk] = *(const short8*)(ovl + (blk * 128 + nl) * WHH_LP + kk * 32 + q * 8);
  __syncthreads();
  // Round 3: Whh rows 256..511 (gate blocks 2,3)
  {
    const float* g = Whh + ((size_t)s * 512 + 256) * 128;
#pragma unroll
    for (int it = 0; it < 16; it++) {
      int j = tid + it * 512;
      float4v v = *(const float4v*)(g + 4 * j);
      u16* dst = ovl + (j >> 5) * WHH_LP + (j & 31) * 4;
      dst[0] = f2bf(v[0]); dst[1] = f2bf(v[1]); dst[2] = f2bf(v[2]); dst[3] = f2bf(v[3]);
    }
  }
  __syncthreads();
#pragma unroll
  for (int blk = 2; blk < 4; blk++)
#pragma unroll
    for (int kk = 0; kk < 4; kk++)
      Af[blk][2 + kk] = *(const short8*)(ovl + ((blk - 2) * 128 + nl) * WHH_LP + kk * 32 + q * 8);
  __syncthreads();

  // ---- E: precompute GNN features into xbuf (= ovl; weights now in registers)
  {
    const int k = tid & 63;
    const int bb = (tid >> 6) & 3;
    const int th = tid >> 8;
    const float wrk = wr_s[k], wvk = wv_s[k], bgk = bg_s[k];
    for (int i = 0; i < T_ / 2; i++) {
      const int t = th * (T_ / 2) + i;
      const float xv = xh_lds[bb][t] * wrk + ag_lds[bb][t] * wvk + bgk;
      ovl[t * (4 * XP_) + bb * XP_ + k] = f2bf(lrelu(xv));
    }
  }
  __syncthreads();

  // ---- recurrent loop. Pipelined: accN = bias + x-part for step t computed
  // BEFORE the barrier that publishes h[t]; post-barrier path = 16 h-MFMAs + act.
  floatx4 accN[4];
  {
    short8 Bx0 = *(const short8*)(ovl + b * XP_ + q * 8);
    short8 Bx1 = *(const short8*)(ovl + b * XP_ + 32 + q * 8);
#pragma unroll
    for (int blk = 0; blk < 4; blk++) {
      accN[blk] = __builtin_amdgcn_mfma_f32_16x16x32_bf16(Af[blk][0], Bx0, bias_init[blk], 0, 0, 0);
      accN[blk] = __builtin_amdgcn_mfma_f32_16x16x32_bf16(Af[blk][1], Bx1, accN[blk], 0, 0, 0);
    }
  }
  float c = 0.0f;
#pragma unroll 2
  for (int t = 0; t < T_; t++) {
    const int p = t & 1, pn = p ^ 1;
    short8 Bh[4];
#pragma unroll
    for (int kk = 0; kk < 4; kk++)
      Bh[kk] = *(const short8*)(hbuf + p * (4 * HP_) + b * HP_ + kk * 32 + q * 8);

    floatx4 acc[4];
#pragma unroll
    for (int blk = 0; blk < 4; blk++) acc[blk] = accN[blk];
#pragma unroll
    for (int kk = 0; kk < 4; kk++)
#pragma unroll
      for (int blk = 0; blk < 4; blk++)
        acc[blk] = __builtin_amdgcn_mfma_f32_16x16x32_bf16(Af[blk][2 + kk], Bh[kk], acc[blk], 0, 0, 0);

    const float gi = sel4(acc[0], rho);
    const float gf = sel4(acc[1], rho);
    const float gg = sel4(acc[2], rho);
    const float go = sel4(acc[3], rho);
    c = sigm(gf) * c + sigm(gi) * tanh_fast(gg);
    const float hh = sigm(go) * tanh_fast(c);
    hbuf[pn * (4 * HP_) + b * HP_ + w * 16 + q * 4 + rho] = f2bf(hh);

    // x-part + bias for step t+1: no dependence on the barrier
    if (t + 1 < T_) {
      short8 Bx0 = *(const short8*)(ovl + (t + 1) * (4 * XP_) + b * XP_ + q * 8);
      short8 Bx1 = *(const short8*)(ovl + (t + 1) * (4 * XP_) + b * XP_ + 32 + q * 8);
#pragma unroll
      for (int blk = 0; blk < 4; blk++) {
        accN[blk] = __builtin_amdgcn_mfma_f32_16x16x32_bf16(Af[blk][0], Bx0, bias_init[blk], 0, 0, 0);
        accN[blk] = __builtin_amdgcn_mfma_f32_16x16x32_bf16(Af[blk][1], Bx1, accN[blk], 0, 0, 0);
      }
    }
    __syncthreads();
  }

  // ---- head: final h is in hbuf[0]
  if (tid < 4 * FUT_) {
    const int bb = tid / FUT_;
    const int f = tid % FUT_;
    float a = blin[f];
#pragma unroll 8
    for (int k = 0; k < HL_; k++) a += b2f(hbuf[bb * HP_ + k]) * Wlin[f * HL_ + k];
    out[((size_t)(bg * 4 + bb) * NH_ + s) * FUT_ + f] = lrelu(a);
  }
}

extern "C" void kernel_launch(void* const* d_in, const int* in_sizes, int n_in,
                              void* d_out, int out_size, void* d_ws, size_t ws_size,
                              hipStream_t stream) {
  const float* dm = (const float*)d_in[0];
  const float* dh = (const float*)d_in[1];
  const int* eidx = (const int*)d_in[2];
  const float* Wroot = (const float*)d_in[3];
  const float* Wrel = (const float*)d_in[4];
  const float* bgnn = (const float*)d_in[5];
  const float* Wih = (const float*)d_in[6];
  const float* Whh = (const float*)d_in[7];
  const float* bih = (const float*)d_in[8];
  const float* bhh = (const float*)d_in[9];
  const float* Wlin = (const float*)d_in[10];
  const float* blin = (const float*)d_in[11];
  float* out = (float*)d_out;

  fused_kernel<<<256, 512, 0, stream>>>(dm, dh, eidx, Wroot, Wrel, bgnn, Wih, Whh,
                                        bih, bhh, Wlin, blin, out);
}